// Round 3
// baseline (1437.610 us; speedup 1.0000x reference)
//
#include <hip/hip_runtime.h>
#include <hip/hip_bf16.h>

typedef __bf16 bf16_t;
typedef __bf16 bf16x8 __attribute__((ext_vector_type(8)));
typedef float f32x4 __attribute__((ext_vector_type(4)));

constexpr int NODEMB = 128;
constexpr int HIDDEN = 128;
constexpr int EDGEMB = 128;
constexpr int NEDGES = 800000;
constexpr int NNODES = 50000;

constexpr int W1S = 296;   // padded K stride (elements) for W1T
constexpr int W2S = 136;   // padded K stride for W2T
constexpr int HS  = 136;   // padded K stride for per-wave H buffer
constexpr int W1_ELEMS = HIDDEN * W1S;   // 37888
constexpr int W2_ELEMS = EDGEMB * W2S;   // 17408
constexpr int TILE_EDGES = 128;
constexpr int NTILES = NEDGES / TILE_EDGES;  // 6250 exactly

// ws layout (bytes)
constexpr size_t WOFF_W    = 0;
constexpr size_t WOFF_NH   = (size_t)(W1_ELEMS + W2_ELEMS) * 2;          // 110,592
constexpr size_t WOFF_NF   = WOFF_NH + (size_t)NNODES * NODEMB * 2;      // +12,800,000
constexpr size_t WOFF_DIST = WOFF_NF + (size_t)NNODES * 4;               // +200,000
constexpr size_t WS_NEEDED = WOFF_DIST + (size_t)NEDGES * 2;             // = 14,710,592

__device__ __forceinline__ bf16x8 cvt8(f32x4 lo, f32x4 hi) {
    bf16x8 t;
    t[0] = (bf16_t)lo[0]; t[1] = (bf16_t)lo[1]; t[2] = (bf16_t)lo[2]; t[3] = (bf16_t)lo[3];
    t[4] = (bf16_t)hi[0]; t[5] = (bf16_t)hi[1]; t[6] = (bf16_t)hi[2]; t[7] = (bf16_t)hi[3];
    return t;
}

// ---------------------------------------------------------------------------
// Prep 1: K-permuted, zero-padded, K-major bf16 weights.
// K-order: [0,128)=dst_hidden (orig rows 2..129), [128,256)=src_hidden
// (orig 132..259), 256=row0, 257=row1, 258=row130, 259=row131, 260=row260.
// ---------------------------------------------------------------------------
__global__ void prep_weights(const float* __restrict__ W1, const float* __restrict__ W2,
                             bf16_t* __restrict__ w1t, bf16_t* __restrict__ w2t) {
    int i = blockIdx.x * blockDim.x + threadIdx.x;
    if (i < W1_ELEMS) {
        int n = i / W1S, k = i - n * W1S;
        float v = 0.f;
        if (k < 128)       v = W1[(2 + k) * HIDDEN + n];
        else if (k < 256)  v = W1[(132 + (k - 128)) * HIDDEN + n];
        else if (k == 256) v = W1[0 * HIDDEN + n];
        else if (k == 257) v = W1[1 * HIDDEN + n];
        else if (k == 258) v = W1[130 * HIDDEN + n];
        else if (k == 259) v = W1[131 * HIDDEN + n];
        else if (k == 260) v = W1[260 * HIDDEN + n];
        w1t[n * W1S + k] = (bf16_t)v;
    } else if (i < W1_ELEMS + W2_ELEMS) {
        int j = i - W1_ELEMS;
        int n = j / W2S, k = j - n * W2S;
        float v = (k < 128) ? W2[k * EDGEMB + n] : 0.f;
        w2t[n * W2S + k] = (bf16_t)v;
    }
}

// ---------------------------------------------------------------------------
// Prep 2: bf16 gather tables (node_hidden, packed node_features, distance).
// Same rounding as in-kernel f32->bf16 cast -> numerically identical.
// ---------------------------------------------------------------------------
__global__ void prep_nodes(const float* __restrict__ nh, const float* __restrict__ nf,
                           const float* __restrict__ dist,
                           bf16_t* __restrict__ nh_b, unsigned* __restrict__ nf_u,
                           bf16_t* __restrict__ dist_b) {
    int i = blockIdx.x * blockDim.x + threadIdx.x;
    constexpr int NH_CHUNKS = NNODES * NODEMB / 8;  // 800000
    if (i < NH_CHUNKS) {
        const f32x4* p = (const f32x4*)nh;
        ((bf16x8*)nh_b)[i] = cvt8(p[2 * i], p[2 * i + 1]);
    }
    if (i < NEDGES) dist_b[i] = (bf16_t)dist[i];
    if (i < NNODES) {
        union { unsigned u; bf16_t h[2]; } c;
        c.h[0] = (bf16_t)nf[2 * i];
        c.h[1] = (bf16_t)nf[2 * i + 1];
        nf_u[i] = c.u;
    }
}

// ---------------------------------------------------------------------------
// Main: 8 waves/block, wave owns 16 edges/tile, all 128 outputs.
// Software-pipelined: indices 2 tiles ahead, gathers 1 tile ahead (issued
// before current tile's MFMAs so HBM latency hides under compute).
// ---------------------------------------------------------------------------
template <bool TAB>
__global__ __launch_bounds__(512, 2) void edge_mlp(
    const float* __restrict__ node_features,
    const float* __restrict__ node_hidden,
    const float* __restrict__ distance,
    const int*   __restrict__ src_idx,
    const int*   __restrict__ dst_idx,
    const float* __restrict__ b1,
    const float* __restrict__ b2,
    const bf16_t* __restrict__ w1t,
    const bf16_t* __restrict__ w2t,
    const bf16_t* __restrict__ nh_b,
    const unsigned* __restrict__ nf_u,
    const bf16_t* __restrict__ dist_b,
    float* __restrict__ out)
{
    __shared__ bf16_t sW[W1_ELEMS + W2_ELEMS];   // 110,592 B
    __shared__ bf16_t sH[8][16][HS];             //  34,816 B

    const int tid = threadIdx.x;

    {   // stage weights into LDS, 16B chunks
        const uint4* gsrc = (const uint4*)w1t;
        uint4* ldst = (uint4*)sW;
        constexpr int CH = (W1_ELEMS + W2_ELEMS) / 8;  // 6912
        for (int i = tid; i < CH; i += 512) ldst[i] = gsrc[i];
    }
    __syncthreads();
    const bf16_t* sW1 = sW;
    const bf16_t* sW2 = sW + W1_ELEMS;

    const int wid  = tid >> 6;
    const int lane = tid & 63;
    const int r    = lane & 15;   // A row / B col within 16-tile
    const int g    = lane >> 4;   // k-subblock selector

    float b1v[8], b2v[8];
    #pragma unroll
    for (int nt = 0; nt < 8; ++nt) {
        b1v[nt] = b1[nt * 16 + r];
        b2v[nt] = b2[nt * 16 + r];
    }

    // gather A fragments for edge e with node indices (di, si)
    auto gather = [&](int di, int si, int e, bf16x8 (&A)[9]) {
        if constexpr (TAB) {
            const bf16x8* dp = (const bf16x8*)(nh_b + (size_t)di * NODEMB);
            const bf16x8* sp = (const bf16x8*)(nh_b + (size_t)si * NODEMB);
            #pragma unroll
            for (int ks = 0; ks < 4; ++ks) A[ks] = dp[ks * 4 + g];
            #pragma unroll
            for (int ks = 0; ks < 4; ++ks) A[4 + ks] = sp[ks * 4 + g];
            bf16x8 t;
            #pragma unroll
            for (int j = 0; j < 8; ++j) t[j] = (bf16_t)0.f;
            if (g == 0) {
                union { unsigned u; bf16_t h[2]; } c1, c2;
                c1.u = nf_u[di]; c2.u = nf_u[si];
                t[0] = c1.h[0]; t[1] = c1.h[1];
                t[2] = c2.h[0]; t[3] = c2.h[1];
                t[4] = dist_b[e];
            }
            A[8] = t;
        } else {
            const f32x4* dh = (const f32x4*)(node_hidden + (size_t)di * NODEMB);
            const f32x4* sh = (const f32x4*)(node_hidden + (size_t)si * NODEMB);
            #pragma unroll
            for (int ks = 0; ks < 4; ++ks)
                A[ks] = cvt8(dh[ks * 8 + g * 2], dh[ks * 8 + g * 2 + 1]);
            #pragma unroll
            for (int ks = 0; ks < 4; ++ks)
                A[4 + ks] = cvt8(sh[ks * 8 + g * 2], sh[ks * 8 + g * 2 + 1]);
            bf16x8 t;
            #pragma unroll
            for (int j = 0; j < 8; ++j) t[j] = (bf16_t)0.f;
            if (g == 0) {
                t[0] = (bf16_t)node_features[di * 2];
                t[1] = (bf16_t)node_features[di * 2 + 1];
                t[2] = (bf16_t)node_features[si * 2];
                t[3] = (bf16_t)node_features[si * 2 + 1];
                t[4] = (bf16_t)distance[e];
            }
            A[8] = t;
        }
    };

    const int stride = (int)gridDim.x;
    auto edge_of = [&](long long tile) {
        int tb = tile < (long long)NTILES ? (int)tile : NTILES - 1;
        return tb * TILE_EDGES + wid * 16 + r;
    };

    // ---- pipeline prologue ----
    int t0 = blockIdx.x;
    int e0 = edge_of(t0);
    int diC = dst_idx[e0], siC = src_idx[e0];
    bf16x8 aC[9];
    gather(diC, siC, e0, aC);
    int e1 = edge_of((long long)t0 + stride);
    int diN = dst_idx[e1], siN = src_idx[e1];

    for (int tile = t0; tile < NTILES; tile += stride) {
        // issue next tile's gathers now (hide latency under MFMAs below)
        bf16x8 aN[9];
        gather(diN, siN, edge_of((long long)tile + stride), aN);
        // prefetch indices two tiles ahead
        int e2 = edge_of((long long)tile + 2LL * stride);
        int di2 = dst_idx[e2], si2 = src_idx[e2];

        // ---- layer 1: [16 x 288] @ [288 x 128] ----
        f32x4 acc[8];
        #pragma unroll
        for (int nt = 0; nt < 8; ++nt) {
            float bv = b1v[nt];
            acc[nt][0] = bv; acc[nt][1] = bv; acc[nt][2] = bv; acc[nt][3] = bv;
        }
        #pragma unroll
        for (int ks = 0; ks < 9; ++ks) {
            #pragma unroll
            for (int nt = 0; nt < 8; ++nt) {
                bf16x8 b = *(const bf16x8*)&sW1[(nt * 16 + r) * W1S + ks * 32 + g * 8];
                acc[nt] = __builtin_amdgcn_mfma_f32_16x16x32_bf16(aC[ks], b, acc[nt], 0, 0, 0);
            }
        }

        // ---- relu + transpose h through per-wave LDS ----
        #pragma unroll
        for (int nt = 0; nt < 8; ++nt) {
            #pragma unroll
            for (int i = 0; i < 4; ++i) {
                float h = acc[nt][i];
                h = h > 0.f ? h : 0.f;
                sH[wid][g * 4 + i][nt * 16 + r] = (bf16_t)h;
            }
        }
        bf16x8 ha[4];
        #pragma unroll
        for (int ks = 0; ks < 4; ++ks)
            ha[ks] = *(const bf16x8*)&sH[wid][r][ks * 32 + g * 8];

        // ---- layer 2: [16 x 128] @ [128 x 128] ----
        f32x4 acc2[8];
        #pragma unroll
        for (int nt = 0; nt < 8; ++nt) {
            float bv = b2v[nt];
            acc2[nt][0] = bv; acc2[nt][1] = bv; acc2[nt][2] = bv; acc2[nt][3] = bv;
        }
        #pragma unroll
        for (int ks = 0; ks < 4; ++ks) {
            #pragma unroll
            for (int nt = 0; nt < 8; ++nt) {
                bf16x8 b = *(const bf16x8*)&sW2[(nt * 16 + r) * W2S + ks * 32 + g * 8];
                acc2[nt] = __builtin_amdgcn_mfma_f32_16x16x32_bf16(ha[ks], b, acc2[nt], 0, 0, 0);
            }
        }

        // ---- relu + nontemporal store (write-once stream; keep L2 for gathers)
        float* ob = out + (size_t)(tile * TILE_EDGES + wid * 16) * EDGEMB;
        #pragma unroll
        for (int nt = 0; nt < 8; ++nt) {
            #pragma unroll
            for (int i = 0; i < 4; ++i) {
                float v = acc2[nt][i];
                v = v > 0.f ? v : 0.f;
                __builtin_nontemporal_store(v, &ob[(g * 4 + i) * EDGEMB + nt * 16 + r]);
            }
        }

        // ---- rotate pipeline registers ----
        #pragma unroll
        for (int ks = 0; ks < 9; ++ks) aC[ks] = aN[ks];
        diN = di2; siN = si2;
    }
}

extern "C" void kernel_launch(void* const* d_in, const int* in_sizes, int n_in,
                              void* d_out, int out_size, void* d_ws, size_t ws_size,
                              hipStream_t stream) {
    const float* node_features = (const float*)d_in[0];
    const float* node_hidden   = (const float*)d_in[1];
    const float* distance      = (const float*)d_in[2];
    const int*   src_idx       = (const int*)d_in[3];
    const int*   dst_idx       = (const int*)d_in[4];
    const float* W1 = (const float*)d_in[5];
    const float* b1 = (const float*)d_in[6];
    const float* W2 = (const float*)d_in[7];
    const float* b2 = (const float*)d_in[8];
    float* out = (float*)d_out;

    bf16_t*   w1t    = (bf16_t*)((char*)d_ws + WOFF_W);
    bf16_t*   w2t    = w1t + W1_ELEMS;
    bf16_t*   nh_b   = (bf16_t*)((char*)d_ws + WOFF_NH);
    unsigned* nf_u   = (unsigned*)((char*)d_ws + WOFF_NF);
    bf16_t*   dist_b = (bf16_t*)((char*)d_ws + WOFF_DIST);

    const int prepThreads = W1_ELEMS + W2_ELEMS;
    prep_weights<<<(prepThreads + 255) / 256, 256, 0, stream>>>(W1, W2, w1t, w2t);

    const bool tab = (ws_size >= WS_NEEDED);  // launch-constant -> graph-safe
    if (tab) {
        constexpr int PREP_MAX = NNODES * NODEMB / 8;  // 800000, >= NEDGES, >= NNODES
        prep_nodes<<<(PREP_MAX + 255) / 256, 256, 0, stream>>>(
            node_hidden, node_features, distance, nh_b, nf_u, dist_b);
        edge_mlp<true><<<256, 512, 0, stream>>>(
            node_features, node_hidden, distance, src_idx, dst_idx, b1, b2,
            w1t, w2t, nh_b, nf_u, dist_b, out);
    } else {
        edge_mlp<false><<<256, 512, 0, stream>>>(
            node_features, node_hidden, distance, src_idx, dst_idx, b1, b2,
            w1t, w2t, nullptr, nullptr, nullptr, out);
    }
}